// Round 2
// baseline (492.676 us; speedup 1.0000x reference)
//
#include <hip/hip_runtime.h>

#define IN_W 224
#define IMG_CH (224*224)        // 50176
#define IMG_SZ (3*IMG_CH)       // 150528
#define P1 37
#define P1SZ (P1*P1)            // 1369
#define STG (21*IN_W)           // 3ch x 7 rows x 224 = 4704 floats

// ---------------- Kernel A: conv1(3x3,s2)+maxpool3+relu -> pool1_ws ----------
// Grid: 640 images x 5 row-bands. Block: 256 threads.
// Per pooled-output row: stage 7 input rows x 3ch into LDS with coalesced
// float4 loads (double-buffered), then wave 0 (lanes px<37) computes all 3
// output channels for 37 sites with SGPR-uniform weights.
__global__ __launch_bounds__(256) void conv1_kernel(
    const float* __restrict__ nodes, const float* __restrict__ depths,
    const float* __restrict__ c1w, const float* __restrict__ c1b,
    const float* __restrict__ d1w, const float* __restrict__ d1b,
    float* __restrict__ pool1_ws)
{
    __shared__ float stage[2][STG];   // 2 x 18816 B = 37.6 KB

    const int band = blockIdx.x % 5;
    const int img  = blockIdx.x / 5;
    const float* in = (img < 320) ? nodes + (size_t)img * IMG_SZ
                                  : depths + (size_t)(img - 320) * IMG_SZ;
    const float* w1 = (img < 320) ? c1w : d1w;
    const float* b1 = (img < 320) ? c1b : d1b;
    const int t = threadIdx.x;

    const int py0 = band * 8;
    const int pyE = (band == 4) ? 37 : py0 + 8;
    const int n = pyE - py0;

    // coalesced stage of rows 6*py .. 6*py+6 for all 3 channels
    auto stage_load = [&](int buf, int py) {
        const int row0 = 6 * py;
        #pragma unroll
        for (int k = 0; k < 5; ++k) {
            const int idx = t + k * 256;
            if (idx < 1176) {                 // 21 rows * 56 float4
                const int r  = idx / 56;      // 0..20  (= ch*7 + u)
                const int c4 = idx - r * 56;
                const int ch = r / 7;
                const int u  = r - ch * 7;
                const float4 v = *(const float4*)(in + ch * IMG_CH
                                                  + (row0 + u) * IN_W + c4 * 4);
                *(float4*)(&stage[buf][r * IN_W + c4 * 4]) = v;
            }
        }
    };

    stage_load(0, py0);
    for (int i = 0; i < n; ++i) {
        __syncthreads();                       // buf (i&1) ready; prev compute done
        if (i + 1 < n) stage_load((i + 1) & 1, py0 + i + 1);

        if (t < P1) {
            const int px = t;
            const float* sb = stage[i & 1];
            float acc[3][9];
            #pragma unroll
            for (int c = 0; c < 3; ++c) {
                const float bv = b1[c];
                #pragma unroll
                for (int q = 0; q < 9; ++q) acc[c][q] = bv;
            }
            #pragma unroll
            for (int ic = 0; ic < 3; ++ic) {
                #pragma unroll
                for (int u = 0; u < 7; ++u) {
                    float row[7];
                    #pragma unroll
                    for (int v = 0; v < 7; ++v)
                        row[v] = sb[(ic * 7 + u) * IN_W + 6 * px + v];
                    // conv row index within pool window: w, kernel row ku
                    #pragma unroll
                    for (int w = 0; w < 3; ++w)
                        #pragma unroll
                        for (int ku = 0; ku < 3; ++ku)
                            if (2 * w + ku == u) {
                                #pragma unroll
                                for (int c = 0; c < 3; ++c)
                                    #pragma unroll
                                    for (int wx = 0; wx < 3; ++wx)
                                        #pragma unroll
                                        for (int kv = 0; kv < 3; ++kv)
                                            acc[c][w * 3 + wx] =
                                                fmaf(row[2 * wx + kv],
                                                     w1[c * 27 + ic * 9 + ku * 3 + kv],
                                                     acc[c][w * 3 + wx]);
                            }
                }
            }
            const int py = py0 + i;
            #pragma unroll
            for (int c = 0; c < 3; ++c) {
                float m = acc[c][0];
                #pragma unroll
                for (int q = 1; q < 9; ++q) m = fmaxf(m, acc[c][q]);
                pool1_ws[((size_t)img * 3 + c) * P1SZ + py * P1 + px] =
                    fmaxf(m, 0.f);
            }
        }
    }
}

// ---------------- Kernel B: conv2(3x3,s2)+maxpool3+relu + linear 36->6 ------
__global__ __launch_bounds__(64) void conv2_kernel(
    const float* __restrict__ pool1_ws,
    const float* __restrict__ c2w, const float* __restrict__ c2b,
    const float* __restrict__ lw,  const float* __restrict__ lb,
    const float* __restrict__ d2w, const float* __restrict__ d2b,
    const float* __restrict__ dlw, const float* __restrict__ dlb,
    float* __restrict__ feat_ws, float* __restrict__ dfeat_ws)
{
    __shared__ float pool2[36];
    const int img = blockIdx.x;
    const float *w2, *b2, *lwp, *lbp;
    float* outp;
    if (img < 320) {
        w2 = c2w; b2 = c2b; lwp = lw; lbp = lb;
        outp = feat_ws + img * 6;
    } else {
        w2 = d2w; b2 = d2b; lwp = dlw; lbp = dlb;
        outp = dfeat_ws + (img - 320) * 6;
    }
    const float* p1 = pool1_ws + (size_t)img * 3 * P1SZ;
    const int t = threadIdx.x;

    if (t < 36) {
        const int qy = t / 6, qx = t % 6;
        float acc[9];
        const float bv = b2[0];
        #pragma unroll
        for (int q = 0; q < 9; ++q) acc[q] = bv;
        #pragma unroll
        for (int ic = 0; ic < 3; ++ic) {
            float p[7][7];
            #pragma unroll
            for (int u = 0; u < 7; ++u)
                #pragma unroll
                for (int v = 0; v < 7; ++v)
                    p[u][v] = p1[ic * P1SZ + (6 * qy + u) * P1 + 6 * qx + v];
            #pragma unroll
            for (int ky = 0; ky < 3; ++ky)
                #pragma unroll
                for (int kx = 0; kx < 3; ++kx)
                    #pragma unroll
                    for (int u = 0; u < 3; ++u)
                        #pragma unroll
                        for (int v = 0; v < 3; ++v)
                            acc[ky * 3 + kx] = fmaf(p[2 * ky + u][2 * kx + v],
                                                    w2[ic * 9 + u * 3 + v],
                                                    acc[ky * 3 + kx]);
        }
        float m = acc[0];
        #pragma unroll
        for (int q = 1; q < 9; ++q) m = fmaxf(m, acc[q]);
        pool2[t] = fmaxf(m, 0.f);
    }
    __syncthreads();
    if (t < 6) {
        float s = lbp[t];
        #pragma unroll
        for (int k = 0; k < 36; ++k) s = fmaf(pool2[k], lwp[t * 36 + k], s);
        outp[t] = s;
    }
}

// ---------------- Kernel C: message passing + fc1/fc2/fc3 -------------------
__global__ __launch_bounds__(256) void head_kernel(
    const float* __restrict__ pos, const float* __restrict__ attmap,
    const float* __restrict__ fmp_w, const float* __restrict__ fmp_b,
    const float* __restrict__ lmp_w, const float* __restrict__ lmp_b,
    const float* __restrict__ fc1_w, const float* __restrict__ fc1_b,
    const float* __restrict__ fc2_w, const float* __restrict__ fc2_b,
    const float* __restrict__ fc3_w, const float* __restrict__ fc3_b,
    const float* __restrict__ feat_ws, const float* __restrict__ dfeat_ws,
    float* __restrict__ out)
{
    __shared__ float na[240];
    __shared__ float msg[240];
    __shared__ float lastb[240];
    __shared__ __align__(16) float x[360];
    __shared__ __align__(16) float h1[180];
    __shared__ float h2[60];
    const int b = blockIdx.x, t = threadIdx.x;

    if (t < 240) {
        const int k = t % 12, m = (t / 12) % 4, f = t / 48;
        na[t] = (k < 6) ? feat_ws[b * 120 + f * 24 + m * 6 + k]
                        : pos[b * 120 + f * 24 + m * 6 + (k - 6)];
    }
    __syncthreads();
    if (t < 240) {
        const int d = t % 12, base = (t / 12) * 12;
        float s1 = fmp_b[d], s2 = lmp_b[d];
        #pragma unroll
        for (int k = 0; k < 12; ++k) {
            const float v = na[base + k];
            s1 = fmaf(v, fmp_w[d * 12 + k], s1);
            s2 = fmaf(v, lmp_w[d * 12 + k], s2);
        }
        msg[t] = s1; lastb[t] = s2;
    }
    __syncthreads();
    if (t < 240) {
        const int d = t % 12, n = (t / 12) % 4, f = t / 48;
        float s = 0.f;
        #pragma unroll
        for (int m = 0; m < 4; ++m)
            s = fmaf(attmap[b * 80 + f * 16 + m * 4 + n], msg[f * 48 + m * 12 + d], s);
        if (f > 0) s += lastb[(f - 1) * 48 + n * 12 + d];
        x[(f * 4 + n) * 18 + d] = s;
    }
    if (t < 120) {
        const int j = t % 6, n = (t / 6) % 4, f = t / 24;
        x[(f * 4 + n) * 18 + 12 + j] = dfeat_ws[b * 120 + f * 24 + n * 6 + j];
    }
    __syncthreads();
    if (t < 180) {
        const float4* wr = (const float4*)(fc1_w + t * 360);
        const float4* xs = (const float4*)x;
        float s = fc1_b[t];
        #pragma unroll 10
        for (int k = 0; k < 90; ++k) {
            const float4 w4 = wr[k]; const float4 x4 = xs[k];
            s = fmaf(w4.x, x4.x, s); s = fmaf(w4.y, x4.y, s);
            s = fmaf(w4.z, x4.z, s); s = fmaf(w4.w, x4.w, s);
        }
        h1[t] = fmaxf(s, 0.f);
    }
    __syncthreads();
    if (t < 60) {
        const float4* wr = (const float4*)(fc2_w + t * 180);
        const float4* hs = (const float4*)h1;
        float s = fc2_b[t];
        #pragma unroll
        for (int k = 0; k < 45; ++k) {
            const float4 w4 = wr[k]; const float4 x4 = hs[k];
            s = fmaf(w4.x, x4.x, s); s = fmaf(w4.y, x4.y, s);
            s = fmaf(w4.z, x4.z, s); s = fmaf(w4.w, x4.w, s);
        }
        h2[t] = fmaxf(s, 0.f);
    }
    __syncthreads();
    if (t < 6) {
        float s = fc3_b[t];
        #pragma unroll
        for (int k = 0; k < 60; ++k) s = fmaf(h2[k], fc3_w[t * 60 + k], s);
        out[b * 6 + t] = s;
    }
}

extern "C" void kernel_launch(void* const* d_in, const int* in_sizes, int n_in,
                              void* d_out, int out_size, void* d_ws, size_t ws_size,
                              hipStream_t stream) {
    const float* nodes  = (const float*)d_in[0];
    const float* pos    = (const float*)d_in[1];
    const float* attmap = (const float*)d_in[2];
    const float* depths = (const float*)d_in[3];
    const float* c1w = (const float*)d_in[4],  *c1b = (const float*)d_in[5];
    const float* c2w = (const float*)d_in[6],  *c2b = (const float*)d_in[7];
    const float* lw  = (const float*)d_in[8],  *lb  = (const float*)d_in[9];
    const float* d1w = (const float*)d_in[10], *d1b = (const float*)d_in[11];
    const float* d2w = (const float*)d_in[12], *d2b = (const float*)d_in[13];
    const float* dlw = (const float*)d_in[14], *dlb = (const float*)d_in[15];
    const float* fmpw = (const float*)d_in[16], *fmpb = (const float*)d_in[17];
    const float* lmpw = (const float*)d_in[18], *lmpb = (const float*)d_in[19];
    const float* fc1w = (const float*)d_in[20], *fc1b = (const float*)d_in[21];
    const float* fc2w = (const float*)d_in[22], *fc2b = (const float*)d_in[23];
    const float* fc3w = (const float*)d_in[24], *fc3b = (const float*)d_in[25];

    float* pool1_ws = (float*)d_ws;                   // 640*3*1369 = 2,628,480 floats
    float* feat_ws  = pool1_ws + 640 * 3 * P1SZ;      // 1920 floats
    float* dfeat_ws = feat_ws + 1920;                 // 1920 floats

    conv1_kernel<<<3200, 256, 0, stream>>>(nodes, depths, c1w, c1b, d1w, d1b,
                                           pool1_ws);
    conv2_kernel<<<640, 64, 0, stream>>>(pool1_ws, c2w, c2b, lw, lb,
                                         d2w, d2b, dlw, dlb, feat_ws, dfeat_ws);
    head_kernel<<<16, 256, 0, stream>>>(pos, attmap, fmpw, fmpb, lmpw, lmpb,
                                        fc1w, fc1b, fc2w, fc2b, fc3w, fc3b,
                                        feat_ws, dfeat_ws, (float*)d_out);
}

// Round 3
// 454.663 us; speedup vs baseline: 1.0836x; 1.0836x over previous
//
#include <hip/hip_runtime.h>

#define IN_W 224
#define IMG_CH (224*224)        // 50176
#define IMG_SZ (3*IMG_CH)       // 150528
#define P1 37
#define P1SZ (P1*P1)            // 1369

// One block per image (640 blocks, 256 thr = 4 waves).
// Wave w computes pooled rows py = w, w+4, ... Each lane l loads float4 at
// col 4l (coalesced 896B/wave-instr), computes conv outputs x=2l,2l+1 for all
// 3 channels and 3 conv rows of the pool window in registers; boundary col via
// __shfl_down. Row-window max in regs, x-pooling via per-wave LDS row buffer.
// pool1 lives in LDS; conv2+pool+linear fused at the end.
__global__ __launch_bounds__(256) void branch_kernel(
    const float* __restrict__ nodes, const float* __restrict__ depths,
    const float* __restrict__ c1w, const float* __restrict__ c1b,
    const float* __restrict__ c2w, const float* __restrict__ c2b,
    const float* __restrict__ lw,  const float* __restrict__ lb,
    const float* __restrict__ d1w, const float* __restrict__ d1b,
    const float* __restrict__ d2w, const float* __restrict__ d2b,
    const float* __restrict__ dlw, const float* __restrict__ dlb,
    float* __restrict__ feat_ws, float* __restrict__ dfeat_ws)
{
    __shared__ float pool1[3 * P1SZ];     // 16.4 KB
    __shared__ float xbuf[4][3][112];     // per-wave conv-row-max buffer, 5.4 KB
    __shared__ float pool2[36];

    const int img = blockIdx.x;
    const float* in;
    const float *w1p, *b1p, *w2, *b2, *lwp, *lbp;
    float* outp;
    if (img < 320) {
        in = nodes + (size_t)img * IMG_SZ;
        w1p = c1w; b1p = c1b; w2 = c2w; b2 = c2b; lwp = lw; lbp = lb;
        outp = feat_ws + img * 6;
    } else {
        in = depths + (size_t)(img - 320) * IMG_SZ;
        w1p = d1w; b1p = d1b; w2 = d2w; b2 = d2b; lwp = dlw; lbp = dlb;
        outp = dfeat_ws + (img - 320) * 6;
    }
    const int t  = threadIdx.x;
    const int wv = t >> 6;
    const int l  = t & 63;

    // conv1 weights/bias into registers (fully unrolled -> no scratch)
    float W[3][3][3][3];   // [oc][ic][ku][kv]
    #pragma unroll
    for (int c = 0; c < 3; ++c)
        #pragma unroll
        for (int ic = 0; ic < 3; ++ic)
            #pragma unroll
            for (int ku = 0; ku < 3; ++ku)
                #pragma unroll
                for (int kv = 0; kv < 3; ++kv)
                    W[c][ic][ku][kv] = w1p[c * 27 + ic * 9 + ku * 3 + kv];
    const float B0 = b1p[0], B1 = b1p[1], B2 = b1p[2];

    // lanes >=56 load a safe clamped address; their results are never used
    const int col4 = (l < 56) ? 4 * l : 220;

    for (int py = wv; py < P1; py += 4) {
        float acc[3][3][2];   // [oc][conv-row-in-window][x-slot]
        #pragma unroll
        for (int c = 0; c < 3; ++c) {
            const float bv = (c == 0) ? B0 : (c == 1) ? B1 : B2;
            #pragma unroll
            for (int w = 0; w < 3; ++w) {
                acc[c][w][0] = bv; acc[c][w][1] = bv;
            }
        }
        #pragma unroll
        for (int ic = 0; ic < 3; ++ic) {
            const float* base = in + ic * IMG_CH + (6 * py) * IN_W + col4;
            #pragma unroll
            for (int u = 0; u < 7; ++u) {
                const float4 v = *(const float4*)(base + u * IN_W);
                const float nx = __shfl_down(v.x, 1);   // col 4l+4
                const float cc[5] = {v.x, v.y, v.z, v.w, nx};
                #pragma unroll
                for (int w = 0; w < 3; ++w)
                    #pragma unroll
                    for (int ku = 0; ku < 3; ++ku)
                        if (2 * w + ku == u) {
                            #pragma unroll
                            for (int c = 0; c < 3; ++c)
                                #pragma unroll
                                for (int kv = 0; kv < 3; ++kv) {
                                    acc[c][w][0] = fmaf(cc[kv],     W[c][ic][ku][kv], acc[c][w][0]);
                                    acc[c][w][1] = fmaf(cc[kv + 2], W[c][ic][ku][kv], acc[c][w][1]);
                                }
                        }
            }
        }
        // max over the 3 conv rows -> per-wave x buffer
        if (l < 56) {
            #pragma unroll
            for (int c = 0; c < 3; ++c) {
                const float m0 = fmaxf(fmaxf(acc[c][0][0], acc[c][1][0]), acc[c][2][0]);
                const float m1 = fmaxf(fmaxf(acc[c][0][1], acc[c][1][1]), acc[c][2][1]);
                xbuf[wv][c][2 * l]     = m0;
                xbuf[wv][c][2 * l + 1] = m1;
            }
        }
        // x-pooling (within-wave LDS use: wave-wide in-order DS ops, no barrier)
        if (l < P1) {
            #pragma unroll
            for (int c = 0; c < 3; ++c) {
                float m = fmaxf(fmaxf(xbuf[wv][c][3 * l], xbuf[wv][c][3 * l + 1]),
                                xbuf[wv][c][3 * l + 2]);
                pool1[c * P1SZ + py * P1 + l] = fmaxf(m, 0.f);
            }
        }
    }
    __syncthreads();

    // conv2 (3->1ch, 3x3, s2) + maxpool3 + relu
    if (t < 36) {
        const int qy = t / 6, qx = t % 6;
        float acc[9];
        const float bv = b2[0];
        #pragma unroll
        for (int q = 0; q < 9; ++q) acc[q] = bv;
        #pragma unroll
        for (int ic = 0; ic < 3; ++ic) {
            float p[7][7];
            #pragma unroll
            for (int u = 0; u < 7; ++u)
                #pragma unroll
                for (int v = 0; v < 7; ++v)
                    p[u][v] = pool1[ic * P1SZ + (6 * qy + u) * P1 + 6 * qx + v];
            #pragma unroll
            for (int ky = 0; ky < 3; ++ky)
                #pragma unroll
                for (int kx = 0; kx < 3; ++kx)
                    #pragma unroll
                    for (int u = 0; u < 3; ++u)
                        #pragma unroll
                        for (int v = 0; v < 3; ++v)
                            acc[ky * 3 + kx] = fmaf(p[2 * ky + u][2 * kx + v],
                                                    w2[ic * 9 + u * 3 + v],
                                                    acc[ky * 3 + kx]);
        }
        float m = acc[0];
        #pragma unroll
        for (int q = 1; q < 9; ++q) m = fmaxf(m, acc[q]);
        pool2[t] = fmaxf(m, 0.f);
    }
    __syncthreads();
    if (t < 6) {
        float s = lbp[t];
        #pragma unroll
        for (int k = 0; k < 36; ++k) s = fmaf(pool2[k], lwp[t * 36 + k], s);
        outp[t] = s;
    }
}

// ---------------- message passing + fc1/fc2/fc3 -----------------------------
__global__ __launch_bounds__(256) void head_kernel(
    const float* __restrict__ pos, const float* __restrict__ attmap,
    const float* __restrict__ fmp_w, const float* __restrict__ fmp_b,
    const float* __restrict__ lmp_w, const float* __restrict__ lmp_b,
    const float* __restrict__ fc1_w, const float* __restrict__ fc1_b,
    const float* __restrict__ fc2_w, const float* __restrict__ fc2_b,
    const float* __restrict__ fc3_w, const float* __restrict__ fc3_b,
    const float* __restrict__ feat_ws, const float* __restrict__ dfeat_ws,
    float* __restrict__ out)
{
    __shared__ float na[240];
    __shared__ float msg[240];
    __shared__ float lastb[240];
    __shared__ __align__(16) float x[360];
    __shared__ __align__(16) float h1[180];
    __shared__ float h2[60];
    const int b = blockIdx.x, t = threadIdx.x;

    if (t < 240) {
        const int k = t % 12, m = (t / 12) % 4, f = t / 48;
        na[t] = (k < 6) ? feat_ws[b * 120 + f * 24 + m * 6 + k]
                        : pos[b * 120 + f * 24 + m * 6 + (k - 6)];
    }
    __syncthreads();
    if (t < 240) {
        const int d = t % 12, base = (t / 12) * 12;
        float s1 = fmp_b[d], s2 = lmp_b[d];
        #pragma unroll
        for (int k = 0; k < 12; ++k) {
            const float v = na[base + k];
            s1 = fmaf(v, fmp_w[d * 12 + k], s1);
            s2 = fmaf(v, lmp_w[d * 12 + k], s2);
        }
        msg[t] = s1; lastb[t] = s2;
    }
    __syncthreads();
    if (t < 240) {
        const int d = t % 12, n = (t / 12) % 4, f = t / 48;
        float s = 0.f;
        #pragma unroll
        for (int m = 0; m < 4; ++m)
            s = fmaf(attmap[b * 80 + f * 16 + m * 4 + n], msg[f * 48 + m * 12 + d], s);
        if (f > 0) s += lastb[(f - 1) * 48 + n * 12 + d];
        x[(f * 4 + n) * 18 + d] = s;
    }
    if (t < 120) {
        const int j = t % 6, n = (t / 6) % 4, f = t / 24;
        x[(f * 4 + n) * 18 + 12 + j] = dfeat_ws[b * 120 + f * 24 + n * 6 + j];
    }
    __syncthreads();
    if (t < 180) {
        const float4* wr = (const float4*)(fc1_w + t * 360);
        const float4* xs = (const float4*)x;
        float s = fc1_b[t];
        #pragma unroll 10
        for (int k = 0; k < 90; ++k) {
            const float4 w4 = wr[k]; const float4 x4 = xs[k];
            s = fmaf(w4.x, x4.x, s); s = fmaf(w4.y, x4.y, s);
            s = fmaf(w4.z, x4.z, s); s = fmaf(w4.w, x4.w, s);
        }
        h1[t] = fmaxf(s, 0.f);
    }
    __syncthreads();
    if (t < 60) {
        const float4* wr = (const float4*)(fc2_w + t * 180);
        const float4* hs = (const float4*)h1;
        float s = fc2_b[t];
        #pragma unroll
        for (int k = 0; k < 45; ++k) {
            const float4 w4 = wr[k]; const float4 x4 = hs[k];
            s = fmaf(w4.x, x4.x, s); s = fmaf(w4.y, x4.y, s);
            s = fmaf(w4.z, x4.z, s); s = fmaf(w4.w, x4.w, s);
        }
        h2[t] = fmaxf(s, 0.f);
    }
    __syncthreads();
    if (t < 6) {
        float s = fc3_b[t];
        #pragma unroll
        for (int k = 0; k < 60; ++k) s = fmaf(h2[k], fc3_w[t * 60 + k], s);
        out[b * 6 + t] = s;
    }
}

extern "C" void kernel_launch(void* const* d_in, const int* in_sizes, int n_in,
                              void* d_out, int out_size, void* d_ws, size_t ws_size,
                              hipStream_t stream) {
    const float* nodes  = (const float*)d_in[0];
    const float* pos    = (const float*)d_in[1];
    const float* attmap = (const float*)d_in[2];
    const float* depths = (const float*)d_in[3];
    const float* c1w = (const float*)d_in[4],  *c1b = (const float*)d_in[5];
    const float* c2w = (const float*)d_in[6],  *c2b = (const float*)d_in[7];
    const float* lw  = (const float*)d_in[8],  *lb  = (const float*)d_in[9];
    const float* d1w = (const float*)d_in[10], *d1b = (const float*)d_in[11];
    const float* d2w = (const float*)d_in[12], *d2b = (const float*)d_in[13];
    const float* dlw = (const float*)d_in[14], *dlb = (const float*)d_in[15];
    const float* fmpw = (const float*)d_in[16], *fmpb = (const float*)d_in[17];
    const float* lmpw = (const float*)d_in[18], *lmpb = (const float*)d_in[19];
    const float* fc1w = (const float*)d_in[20], *fc1b = (const float*)d_in[21];
    const float* fc2w = (const float*)d_in[22], *fc2b = (const float*)d_in[23];
    const float* fc3w = (const float*)d_in[24], *fc3b = (const float*)d_in[25];

    float* feat_ws  = (float*)d_ws;          // 1920 floats
    float* dfeat_ws = feat_ws + 1920;        // 1920 floats

    branch_kernel<<<640, 256, 0, stream>>>(
        nodes, depths, c1w, c1b, c2w, c2b, lw, lb,
        d1w, d1b, d2w, d2b, dlw, dlb, feat_ws, dfeat_ws);

    head_kernel<<<16, 256, 0, stream>>>(
        pos, attmap, fmpw, fmpb, lmpw, lmpb,
        fc1w, fc1b, fc2w, fc2b, fc3w, fc3b,
        feat_ws, dfeat_ws, (float*)d_out);
}